// Round 5
// baseline (494.725 us; speedup 1.0000x reference)
//
#include <hip/hip_runtime.h>

#define NN 100000
#define NE 1600000
#define CH 128
#define BCAP 64  // bucket capacity per node; P(deg>64 | Poisson(16)) ~ 1e-18

typedef __attribute__((ext_vector_type(8))) short bf16x8;
typedef __attribute__((ext_vector_type(4))) float f32x4;
typedef unsigned int uint;
typedef unsigned short ushort;

__device__ __forceinline__ ushort f2b(float f) {
    uint u = __builtin_bit_cast(uint, f);
    uint r = (u + 0x7fff + ((u >> 16) & 1)) >> 16;
    return (ushort)r;
}
__device__ __forceinline__ float blo(uint v) { return __builtin_bit_cast(float, v << 16); }
__device__ __forceinline__ float bhi(uint v) { return __builtin_bit_cast(float, v & 0xffff0000u); }

__device__ __forceinline__ void acc8(float* a, uint4 v) {
    a[0] += blo(v.x); a[1] += bhi(v.x);
    a[2] += blo(v.y); a[3] += bhi(v.y);
    a[4] += blo(v.z); a[5] += bhi(v.z);
    a[6] += blo(v.w); a[7] += bhi(v.w);
}

// ---------------- single-pass padded-bucket CSR ----------------
// bucket[d][pos] = src, pos = atomic rank. Order within a bucket is irrelevant
// for mean aggregation, so one atomic edge pass replaces count+scan+fill.

__global__ __launch_bounds__(256) void k_scatter(const int* __restrict__ src, const int* __restrict__ dst,
                                                 int* __restrict__ cnt, int* __restrict__ bucket) {
    int e = blockIdx.x * 256 + threadIdx.x;
    if (e < NE) {
        int d = dst[e];
        int pos = atomicAdd(&cnt[d], 1);
        if (pos < BCAP) bucket[(size_t)d * BCAP + pos] = src[e];
    }
}

// ---------------- casts ----------------

// x [NN][128] fp32 -> plane-sliced bf16: xb[p][n][32], p = blockIdx.y in [0,4)
__global__ __launch_bounds__(256) void k_castx(const float* __restrict__ x, ushort* __restrict__ xb) {
    int n = blockIdx.x * 256 + threadIdx.x;
    int p = blockIdx.y;
    if (n >= NN) return;
    const float4* sp = (const float4*)(x + (size_t)n * 128 + p * 32);
    uint4 o[4];
    ushort* op = (ushort*)o;
    #pragma unroll
    for (int q = 0; q < 8; ++q) {
        float4 v = sp[q];
        op[q * 4 + 0] = f2b(v.x);
        op[q * 4 + 1] = f2b(v.y);
        op[q * 4 + 2] = f2b(v.z);
        op[q * 4 + 3] = f2b(v.w);
    }
    uint4* dp = (uint4*)(xb + ((size_t)p * NN + n) * 32);
    dp[0] = o[0]; dp[1] = o[1]; dp[2] = o[2]; dp[3] = o[3];
}

// Bt[n][k] (n-major, K=256 contiguous): k<128 -> Wl[k][n], else Wr[k-128][n]
__global__ __launch_bounds__(256) void k_castw(const float* __restrict__ Wl, const float* __restrict__ Wr,
                                               ushort* __restrict__ Bt) {
    int i = blockIdx.x * 256 + threadIdx.x;  // 128*256
    int n = i >> 8, k = i & 255;
    float v = (k < 128) ? Wl[k * 128 + n] : Wr[(k - 128) * 128 + n];
    Bt[i] = f2b(v);
}

// ---------------- mean aggregation, 4 planes x 32ch (64B rows) ----------------
// grid (4, NN/64); (p + 4y)%8 pins plane p to XCD pair {p, p+4}.
// 4 lanes per node (32ch = 4 x uint4), 64 nodes per block, unroll 8 for MLP.

__global__ __launch_bounds__(256) void k_agg(const uint4* __restrict__ feat, const int* __restrict__ bucket,
                                             const int* __restrict__ cnt, uint4* __restrict__ outb) {
    int plane = blockIdx.x;
    int n = blockIdx.y * 64 + (threadIdx.x >> 2);
    int h = threadIdx.x & 3;
    if (n >= NN) return;
    int deg = cnt[n];
    int d = deg < BCAP ? deg : BCAP;
    const int* bp = bucket + (size_t)n * BCAP;
    const uint4* fp = feat + (size_t)plane * (NN * 4) + h;
    float a[8] = {};
    int i = 0;
    for (; i + 8 <= d; i += 8) {
        int c[8];
        uint4 v[8];
        #pragma unroll
        for (int j = 0; j < 8; ++j) c[j] = bp[i + j];
        #pragma unroll
        for (int j = 0; j < 8; ++j) v[j] = fp[(size_t)c[j] * 4];
        #pragma unroll
        for (int j = 0; j < 8; ++j) acc8(a, v[j]);
    }
    for (; i < d; ++i) acc8(a, fp[(size_t)bp[i] * 4]);
    float id = 1.0f / fmaxf((float)deg, 1.0f);
    uint4 r;
    r.x = (uint)f2b(a[0] * id) | ((uint)f2b(a[1] * id) << 16);
    r.y = (uint)f2b(a[2] * id) | ((uint)f2b(a[3] * id) << 16);
    r.z = (uint)f2b(a[4] * id) | ((uint)f2b(a[5] * id) << 16);
    r.w = (uint)f2b(a[6] * id) | ((uint)f2b(a[7] * id) << 16);
    outb[((size_t)plane * NN + n) * 4 + h] = r;
}

// ---------------- MFMA GEMM: out = relu([Am | Ax] @ Bt^T + bias) ----------------
// A operands plane-sliced [4][N][32] bf16. M x 128, K=256. BM=128/block, 32 rows/wave.

template <bool WB16>
__global__ __launch_bounds__(256) void k_gemm(const ushort* __restrict__ Am, const ushort* Ax,
                                              const ushort* __restrict__ Bt, const float* __restrict__ bias,
                                              void* outp, int M) {
    int lane = threadIdx.x & 63;
    int wave = threadIdx.x >> 6;
    int bm = blockIdx.x * 128 + wave * 32;
    int l16 = lane & 15;
    int lk8 = (lane >> 4) * 8;

    f32x4 acc[2][8] = {};
    #pragma unroll
    for (int kt = 0; kt < 8; ++kt) {
        const ushort* A = (kt < 4) ? Am : Ax;
        int kA = (kt & 3) * 32 + lk8;           // channel offset in [0,128), multiple of 8
        int p = kA >> 5, ko = kA & 31;          // plane (32ch), offset within plane row
        bf16x8 af[2];
        #pragma unroll
        for (int mt = 0; mt < 2; ++mt) {
            int row = bm + mt * 16 + l16;
            row = row < M ? row : M - 1;
            af[mt] = *(const bf16x8*)(A + ((size_t)p * NN + row) * 32 + ko);
        }
        int kB = kt * 32 + lk8;
        #pragma unroll
        for (int nt = 0; nt < 8; ++nt) {
            bf16x8 bfr = *(const bf16x8*)(Bt + (size_t)(nt * 16 + l16) * 256 + kB);
            acc[0][nt] = __builtin_amdgcn_mfma_f32_16x16x32_bf16(af[0], bfr, acc[0][nt], 0, 0, 0);
            acc[1][nt] = __builtin_amdgcn_mfma_f32_16x16x32_bf16(af[1], bfr, acc[1][nt], 0, 0, 0);
        }
    }
    // C/D layout: col = lane&15, row = (lane>>4)*4 + reg
    int mr0 = (lane >> 4) * 4;
    #pragma unroll
    for (int mt = 0; mt < 2; ++mt) {
        #pragma unroll
        for (int r = 0; r < 4; ++r) {
            int m = bm + mt * 16 + mr0 + r;
            if (m < M) {
                #pragma unroll
                for (int nt = 0; nt < 8; ++nt) {
                    int nch = nt * 16 + l16;
                    float v = acc[mt][nt][r] + bias[nch];
                    v = v > 0.f ? v : 0.f;
                    if (WB16) {
                        // h plane-sliced: plane = nch>>5, ch = nch&31
                        ((ushort*)outp)[(((size_t)(nch >> 5) * NN + m) * 32) + (nch & 31)] = f2b(v);
                    } else {
                        ((float*)outp)[(size_t)m * 128 + nch] = v;
                    }
                }
            }
        }
    }
}

// ---------------- launch ----------------

static inline size_t alignup(size_t x) { return (x + 255) & ~(size_t)255; }

extern "C" void kernel_launch(void* const* d_in, const int* in_sizes, int n_in,
                              void* d_out, int out_size, void* d_ws, size_t ws_size,
                              hipStream_t stream) {
    const float* x   = (const float*)d_in[0];
    const int* edge  = (const int*)d_in[1];
    const float* Wl1 = (const float*)d_in[2];
    const float* Wr1 = (const float*)d_in[3];
    const float* b1  = (const float*)d_in[4];
    const float* Wl2 = (const float*)d_in[5];
    const float* Wr2 = (const float*)d_in[6];
    const float* b2  = (const float*)d_in[7];
    float* out = (float*)d_out;

    const int* srcp = edge;
    const int* dstp = edge + NE;

    char* w = (char*)d_ws;
    int* cnt = (int*)w;       w += alignup((size_t)NN * 4);
    ushort* xb = (ushort*)w;  w += alignup((size_t)NN * CH * 2);  // plane-sliced; reused as h
    ushort* mb = (ushort*)w;  w += alignup((size_t)NN * CH * 2);  // plane-sliced mean
    ushort* Bt1 = (ushort*)w; w += alignup((size_t)128 * 256 * 2);
    ushort* Bt2 = (ushort*)w; w += alignup((size_t)128 * 256 * 2);
    // buckets live in d_out (25.6 MB of 51.2 MB): dead before gemm2 writes output
    int* bucket = (int*)d_out;

    hipMemsetAsync(cnt, 0, (size_t)NN * 4, stream);

    k_scatter<<<(NE + 255) / 256, 256, 0, stream>>>(srcp, dstp, cnt, bucket);

    k_castx<<<dim3((NN + 255) / 256, 4), 256, 0, stream>>>(x, xb);
    k_castw<<<128, 256, 0, stream>>>(Wl1, Wr1, Bt1);
    k_castw<<<128, 256, 0, stream>>>(Wl2, Wr2, Bt2);

    int gg = (NN + 127) / 128;
    dim3 ag(4, (NN + 63) / 64);
    // layer 1: agg(xb) -> mb; h = relu([mb|xb]@B1) bf16 plane-sliced, in place over xb
    k_agg<<<ag, 256, 0, stream>>>((const uint4*)xb, bucket, cnt, (uint4*)mb);
    k_gemm<true><<<gg, 256, 0, stream>>>(mb, xb, Bt1, b1, (void*)xb, NN);
    // layer 2: agg(h) -> mb; out = relu([mb|h]@B2) fp32 row-major (overwrites buckets)
    k_agg<<<ag, 256, 0, stream>>>((const uint4*)xb, bucket, cnt, (uint4*)mb);
    k_gemm<false><<<gg, 256, 0, stream>>>(mb, xb, Bt2, b2, (void*)out, NN);
}

// Round 6
// 422.570 us; speedup vs baseline: 1.1708x; 1.1708x over previous
//
#include <hip/hip_runtime.h>

#define NN 100000
#define NE 1600000
#define CH 128

#define PART 512               // nodes per partition
#define NP 196                 // ceil(NN/PART)
#define PCAP 8704              // pair capacity per partition (lambda~8163, +6 sd)
#define EPB 4096               // edges per bin block
#define NB 391                 // ceil(NE/EPB)
#define SCAP 64                // LDS slot cap per (block, partition); lambda~21

typedef __attribute__((ext_vector_type(8))) short bf16x8;
typedef __attribute__((ext_vector_type(4))) float f32x4;
typedef unsigned int uint;
typedef unsigned short ushort;

__device__ __forceinline__ ushort f2b(float f) {
    uint u = __builtin_bit_cast(uint, f);
    uint r = (u + 0x7fff + ((u >> 16) & 1)) >> 16;
    return (ushort)r;
}
__device__ __forceinline__ float blo(uint v) { return __builtin_bit_cast(float, v << 16); }
__device__ __forceinline__ float bhi(uint v) { return __builtin_bit_cast(float, v & 0xffff0000u); }

__device__ __forceinline__ void acc8(float* a, uint4 v) {
    a[0] += blo(v.x); a[1] += bhi(v.x);
    a[2] += blo(v.y); a[3] += bhi(v.y);
    a[4] += blo(v.z); a[5] += bhi(v.z);
    a[6] += blo(v.w); a[7] += bhi(v.w);
}

// ---------------- pass 1: LDS-binned edge partitioning ----------------
// pair = (dst_local << 17) | src ; partition p = dst >> 9.

__global__ __launch_bounds__(1024) void k_bin(const int* __restrict__ src, const int* __restrict__ dst,
                                              uint* __restrict__ pcnt, uint* __restrict__ pairbuf) {
    __shared__ uint slots[NP * SCAP];  // 50.2 KB
    __shared__ uint lcnt[NP];
    __shared__ uint lbase[NP];
    int tid = threadIdx.x;
    if (tid < NP) lcnt[tid] = 0;
    __syncthreads();
    int e0 = blockIdx.x * EPB + tid;
    #pragma unroll
    for (int j = 0; j < EPB / 1024; ++j) {
        int e = e0 + j * 1024;
        if (e < NE) {
            int d = dst[e];
            int s = src[e];
            int p = d >> 9;
            uint pair = ((uint)(d & 511) << 17) | (uint)s;
            uint pos = atomicAdd(&lcnt[p], 1u);
            if (pos < SCAP) slots[p * SCAP + pos] = pair;
        }
    }
    __syncthreads();
    if (tid < NP) {
        uint c = lcnt[tid];
        c = c < SCAP ? c : SCAP;
        lcnt[tid] = c;
        lbase[tid] = atomicAdd(&pcnt[tid], c);
    }
    __syncthreads();
    for (int t = tid; t < NP * SCAP; t += 1024) {
        int p = t >> 6;
        uint s = (uint)(t & (SCAP - 1));
        if (s < lcnt[p]) {
            uint idx = lbase[p] + s;
            if (idx < PCAP) pairbuf[(size_t)p * PCAP + idx] = slots[t];
        }
    }
}

// ---------------- pass 2: per-partition LDS CSR build ----------------
// Emits nbrG (partition-padded CSR, coalesced) + pack[n] = start | (deg<<21).

__global__ __launch_bounds__(256) void k_csr(const uint* __restrict__ pcnt, const uint* __restrict__ pairbuf,
                                             int* __restrict__ nbrG, uint* __restrict__ pack) {
    __shared__ uint pairs[PCAP];   // 34.8 KB
    __shared__ uint cnt[PART];
    __shared__ uint rowptr[PART + 1];
    __shared__ uint tsum[256];
    int tid = threadIdx.x;
    int p = blockIdx.x;
    uint tot = pcnt[p];
    tot = tot < PCAP ? tot : PCAP;
    for (uint i = tid; i < tot; i += 256) pairs[i] = pairbuf[(size_t)p * PCAP + i];
    cnt[tid] = 0;
    cnt[tid + 256] = 0;
    __syncthreads();
    for (uint i = tid; i < tot; i += 256) atomicAdd(&cnt[pairs[i] >> 17], 1u);
    __syncthreads();
    // exclusive scan over 512 counters (2 per thread + Hillis-Steele over 256)
    uint a = cnt[2 * tid], b = cnt[2 * tid + 1];
    uint s = a + b;
    tsum[tid] = s;
    __syncthreads();
    for (int off = 1; off < 256; off <<= 1) {
        uint t = (tid >= off) ? tsum[tid - off] : 0;
        __syncthreads();
        tsum[tid] += t;
        __syncthreads();
    }
    uint excl = tsum[tid] - s;
    rowptr[2 * tid] = excl;
    rowptr[2 * tid + 1] = excl + a;
    if (tid == 255) rowptr[512] = excl + s;
    __syncthreads();
    cnt[tid] = 0;  // reuse as fill counters
    cnt[tid + 256] = 0;
    __syncthreads();
    for (uint i = tid; i < tot; i += 256) {
        uint u = pairs[i];
        uint dl = u >> 17;
        uint pos = rowptr[dl] + atomicAdd(&cnt[dl], 1u);
        nbrG[(size_t)p * PCAP + pos] = (int)(u & 0x1FFFFu);  // L2-hot 35 KB window
    }
    #pragma unroll
    for (int t = tid; t < PART; t += 256) {
        int n = p * PART + t;
        if (n < NN) {
            uint deg = rowptr[t + 1] - rowptr[t];
            pack[n] = ((uint)(p * PCAP) + rowptr[t]) | (deg << 21);
        }
    }
}

// ---------------- casts ----------------

// x [NN][128] fp32 -> plane-sliced bf16: xb[p][n][16], p = blockIdx.y in [0,8)
__global__ __launch_bounds__(256) void k_castx(const float* __restrict__ x, ushort* __restrict__ xb) {
    int n = blockIdx.x * 256 + threadIdx.x;
    int p = blockIdx.y;
    if (n >= NN) return;
    const float4* sp = (const float4*)(x + (size_t)n * 128 + p * 16);
    uint4 o[2];
    ushort* op = (ushort*)o;
    #pragma unroll
    for (int q = 0; q < 4; ++q) {
        float4 v = sp[q];
        op[q * 4 + 0] = f2b(v.x);
        op[q * 4 + 1] = f2b(v.y);
        op[q * 4 + 2] = f2b(v.z);
        op[q * 4 + 3] = f2b(v.w);
    }
    uint4* dp = (uint4*)(xb + ((size_t)p * NN + n) * 16);
    dp[0] = o[0];
    dp[1] = o[1];
}

// Bt[n][k] (n-major, K=256 contiguous): k<128 -> Wl[k][n], else Wr[k-128][n]
__global__ __launch_bounds__(256) void k_castw(const float* __restrict__ Wl, const float* __restrict__ Wr,
                                               ushort* __restrict__ Bt) {
    int i = blockIdx.x * 256 + threadIdx.x;  // 128*256
    int n = i >> 8, k = i & 255;
    float v = (k < 128) ? Wl[k * 128 + n] : Wr[(k - 128) * 128 + n];
    Bt[i] = f2b(v);
}

// ---------------- mean aggregation (round-4 config: 8 planes x 16ch, uint4) ----------------
// grid (8, NN/128); plane = blockIdx.x pins plane<->XCD via linear%8.
// 2 lanes per node, 128 nodes per block.

__global__ __launch_bounds__(256) void k_agg(const uint4* __restrict__ feat, const int* __restrict__ nbrG,
                                             const uint* __restrict__ pack, uint4* __restrict__ outb) {
    int plane = blockIdx.x;
    int n = blockIdx.y * 128 + (threadIdx.x >> 1);
    int h = threadIdx.x & 1;
    if (n >= NN) return;
    uint u = pack[n];
    int s = (int)(u & 0x1FFFFFu);
    int d = (int)(u >> 21);
    const int* bp = nbrG + s;
    const uint4* fp = feat + (size_t)plane * (NN * 2) + h;
    float a[8] = {};
    int i = 0;
    for (; i + 4 <= d; i += 4) {
        int c0 = bp[i], c1 = bp[i + 1], c2 = bp[i + 2], c3 = bp[i + 3];
        uint4 v0 = fp[(size_t)c0 * 2];
        uint4 v1 = fp[(size_t)c1 * 2];
        uint4 v2 = fp[(size_t)c2 * 2];
        uint4 v3 = fp[(size_t)c3 * 2];
        acc8(a, v0);
        acc8(a, v1);
        acc8(a, v2);
        acc8(a, v3);
    }
    for (; i < d; ++i) acc8(a, fp[(size_t)bp[i] * 2]);
    float id = 1.0f / fmaxf((float)d, 1.0f);
    uint4 r;
    r.x = (uint)f2b(a[0] * id) | ((uint)f2b(a[1] * id) << 16);
    r.y = (uint)f2b(a[2] * id) | ((uint)f2b(a[3] * id) << 16);
    r.z = (uint)f2b(a[4] * id) | ((uint)f2b(a[5] * id) << 16);
    r.w = (uint)f2b(a[6] * id) | ((uint)f2b(a[7] * id) << 16);
    outb[((size_t)plane * NN + n) * 2 + h] = r;
}

// ---------------- MFMA GEMM: out = relu([Am | Ax] @ Bt^T + bias) ----------------
// A operands plane-sliced [8][N][16] bf16. M x 128, K=256. BM=128/block, 32 rows/wave.

template <bool WB16>
__global__ __launch_bounds__(256) void k_gemm(const ushort* __restrict__ Am, const ushort* Ax,
                                              const ushort* __restrict__ Bt, const float* __restrict__ bias,
                                              void* outp, int M) {
    int lane = threadIdx.x & 63;
    int wave = threadIdx.x >> 6;
    int bm = blockIdx.x * 128 + wave * 32;
    int l16 = lane & 15;
    int lk8 = (lane >> 4) * 8;

    f32x4 acc[2][8] = {};
    #pragma unroll
    for (int kt = 0; kt < 8; ++kt) {
        const ushort* A = (kt < 4) ? Am : Ax;
        int kA = (kt & 3) * 32 + lk8;           // channel offset in [0,128), multiple of 8
        int p = kA >> 4, ko = kA & 15;          // plane (16ch), offset within plane row
        bf16x8 af[2];
        #pragma unroll
        for (int mt = 0; mt < 2; ++mt) {
            int row = bm + mt * 16 + l16;
            row = row < M ? row : M - 1;
            af[mt] = *(const bf16x8*)(A + ((size_t)p * NN + row) * 16 + ko);
        }
        int kB = kt * 32 + lk8;
        #pragma unroll
        for (int nt = 0; nt < 8; ++nt) {
            bf16x8 bfr = *(const bf16x8*)(Bt + (size_t)(nt * 16 + l16) * 256 + kB);
            acc[0][nt] = __builtin_amdgcn_mfma_f32_16x16x32_bf16(af[0], bfr, acc[0][nt], 0, 0, 0);
            acc[1][nt] = __builtin_amdgcn_mfma_f32_16x16x32_bf16(af[1], bfr, acc[1][nt], 0, 0, 0);
        }
    }
    // C/D layout: col = lane&15, row = (lane>>4)*4 + reg
    int mr0 = (lane >> 4) * 4;
    #pragma unroll
    for (int mt = 0; mt < 2; ++mt) {
        #pragma unroll
        for (int r = 0; r < 4; ++r) {
            int m = bm + mt * 16 + mr0 + r;
            if (m < M) {
                #pragma unroll
                for (int nt = 0; nt < 8; ++nt) {
                    float v = acc[mt][nt][r] + bias[nt * 16 + l16];
                    v = v > 0.f ? v : 0.f;
                    if (WB16) {
                        // h plane-sliced: plane = nt, ch = l16
                        ((ushort*)outp)[((size_t)nt * NN + m) * 16 + l16] = f2b(v);
                    } else {
                        ((float*)outp)[(size_t)m * 128 + nt * 16 + l16] = v;
                    }
                }
            }
        }
    }
}

// ---------------- launch ----------------

static inline size_t alignup(size_t x) { return (x + 255) & ~(size_t)255; }

extern "C" void kernel_launch(void* const* d_in, const int* in_sizes, int n_in,
                              void* d_out, int out_size, void* d_ws, size_t ws_size,
                              hipStream_t stream) {
    const float* x   = (const float*)d_in[0];
    const int* edge  = (const int*)d_in[1];
    const float* Wl1 = (const float*)d_in[2];
    const float* Wr1 = (const float*)d_in[3];
    const float* b1  = (const float*)d_in[4];
    const float* Wl2 = (const float*)d_in[5];
    const float* Wr2 = (const float*)d_in[6];
    const float* b2  = (const float*)d_in[7];
    float* out = (float*)d_out;

    const int* srcp = edge;
    const int* dstp = edge + NE;

    // pairbuf + partition-padded CSR live in d_out (13.6 MB of 51.2 MB);
    // both dead before gemm2 writes the real output.
    uint* pairbuf = (uint*)d_out;                       // NP*PCAP uints = 6.8 MB
    int* nbrG = (int*)d_out + (size_t)NP * PCAP;        // NP*PCAP ints  = 6.8 MB

    char* w = (char*)d_ws;
    uint* pcnt = (uint*)w;    w += alignup((size_t)NP * 4);
    uint* pack = (uint*)w;    w += alignup((size_t)NN * 4);
    ushort* xb = (ushort*)w;  w += alignup((size_t)NN * CH * 2);  // plane-sliced; reused as h
    ushort* mb = (ushort*)w;  w += alignup((size_t)NN * CH * 2);  // plane-sliced mean
    ushort* Bt1 = (ushort*)w; w += alignup((size_t)128 * 256 * 2);
    ushort* Bt2 = (ushort*)w; w += alignup((size_t)128 * 256 * 2);

    hipMemsetAsync(pcnt, 0, (size_t)NP * 4, stream);

    k_bin<<<NB, 1024, 0, stream>>>(srcp, dstp, pcnt, pairbuf);
    k_csr<<<NP, 256, 0, stream>>>(pcnt, pairbuf, nbrG, pack);

    k_castx<<<dim3((NN + 255) / 256, 8), 256, 0, stream>>>(x, xb);
    k_castw<<<128, 256, 0, stream>>>(Wl1, Wr1, Bt1);
    k_castw<<<128, 256, 0, stream>>>(Wl2, Wr2, Bt2);

    int gg = (NN + 127) / 128;
    dim3 ag(8, (NN + 127) / 128);
    // layer 1: agg(xb) -> mb; h = relu([mb|xb]@B1) bf16 plane-sliced, in place over xb
    k_agg<<<ag, 256, 0, stream>>>((const uint4*)xb, nbrG, pack, (uint4*)mb);
    k_gemm<true><<<gg, 256, 0, stream>>>(mb, xb, Bt1, b1, (void*)xb, NN);
    // layer 2: agg(h) -> mb; out = relu([mb|h]@B2) fp32 row-major (overwrites pairbuf/nbrG)
    k_agg<<<ag, 256, 0, stream>>>((const uint4*)xb, nbrG, pack, (uint4*)mb);
    k_gemm<false><<<gg, 256, 0, stream>>>(mb, xb, Bt2, b2, (void*)out, NN);
}

// Round 7
// 383.803 us; speedup vs baseline: 1.2890x; 1.1010x over previous
//
#include <hip/hip_runtime.h>

#define NN 100000
#define NE 1600000
#define CH 128

#define PART 512               // nodes per partition
#define NP 196                 // ceil(NN/PART)
#define PCAP 8704              // pair capacity per partition (lambda~8163, +6 sd)
#define EPB 4096               // edges per bin block
#define NB 391                 // ceil(NE/EPB)
#define SCAP 64                // LDS slot cap per (block, partition); lambda~21
#define SLAB 3072              // agg: LDS slab cap (128 nodes, lambda~2048, +22 sd)

typedef __attribute__((ext_vector_type(8))) short bf16x8;
typedef __attribute__((ext_vector_type(4))) float f32x4;
typedef unsigned int uint;
typedef unsigned short ushort;

__device__ __forceinline__ ushort f2b(float f) {
    uint u = __builtin_bit_cast(uint, f);
    uint r = (u + 0x7fff + ((u >> 16) & 1)) >> 16;
    return (ushort)r;
}
__device__ __forceinline__ float blo(uint v) { return __builtin_bit_cast(float, v << 16); }
__device__ __forceinline__ float bhi(uint v) { return __builtin_bit_cast(float, v & 0xffff0000u); }

__device__ __forceinline__ void acc8(float* a, uint4 v) {
    a[0] += blo(v.x); a[1] += bhi(v.x);
    a[2] += blo(v.y); a[3] += bhi(v.y);
    a[4] += blo(v.z); a[5] += bhi(v.z);
    a[6] += blo(v.w); a[7] += bhi(v.w);
}

// ---------------- pass 1: LDS-binned edge partitioning ----------------
// pair = (dst_local << 17) | src ; partition p = dst >> 9.

__global__ __launch_bounds__(1024) void k_bin(const int* __restrict__ src, const int* __restrict__ dst,
                                              uint* __restrict__ pcnt, uint* __restrict__ pairbuf) {
    __shared__ uint slots[NP * SCAP];  // 50.2 KB
    __shared__ uint lcnt[NP];
    __shared__ uint lbase[NP];
    int tid = threadIdx.x;
    if (tid < NP) lcnt[tid] = 0;
    __syncthreads();
    int e0 = blockIdx.x * EPB + tid;
    #pragma unroll
    for (int j = 0; j < EPB / 1024; ++j) {
        int e = e0 + j * 1024;
        if (e < NE) {
            int d = dst[e];
            int s = src[e];
            int p = d >> 9;
            uint pair = ((uint)(d & 511) << 17) | (uint)s;
            uint pos = atomicAdd(&lcnt[p], 1u);
            if (pos < SCAP) slots[p * SCAP + pos] = pair;
        }
    }
    __syncthreads();
    if (tid < NP) {
        uint c = lcnt[tid];
        c = c < SCAP ? c : SCAP;
        lcnt[tid] = c;
        lbase[tid] = atomicAdd(&pcnt[tid], c);
    }
    __syncthreads();
    for (int t = tid; t < NP * SCAP; t += 1024) {
        int p = t >> 6;
        uint s = (uint)(t & (SCAP - 1));
        if (s < lcnt[p]) {
            uint idx = lbase[p] + s;
            if (idx < PCAP) pairbuf[(size_t)p * PCAP + idx] = slots[t];
        }
    }
}

// ---------------- pass 2: per-partition LDS CSR build ----------------
// Emits nbrG (partition-padded CSR, coalesced) + pack[n] = start | (deg<<21).

__global__ __launch_bounds__(256) void k_csr(const uint* __restrict__ pcnt, const uint* __restrict__ pairbuf,
                                             int* __restrict__ nbrG, uint* __restrict__ pack) {
    __shared__ uint pairs[PCAP];   // 34.8 KB
    __shared__ uint cnt[PART];
    __shared__ uint rowptr[PART + 1];
    __shared__ uint tsum[256];
    int tid = threadIdx.x;
    int p = blockIdx.x;
    uint tot = pcnt[p];
    tot = tot < PCAP ? tot : PCAP;
    for (uint i = tid; i < tot; i += 256) pairs[i] = pairbuf[(size_t)p * PCAP + i];
    cnt[tid] = 0;
    cnt[tid + 256] = 0;
    __syncthreads();
    for (uint i = tid; i < tot; i += 256) atomicAdd(&cnt[pairs[i] >> 17], 1u);
    __syncthreads();
    // exclusive scan over 512 counters (2 per thread + Hillis-Steele over 256)
    uint a = cnt[2 * tid], b = cnt[2 * tid + 1];
    uint s = a + b;
    tsum[tid] = s;
    __syncthreads();
    for (int off = 1; off < 256; off <<= 1) {
        uint t = (tid >= off) ? tsum[tid - off] : 0;
        __syncthreads();
        tsum[tid] += t;
        __syncthreads();
    }
    uint excl = tsum[tid] - s;
    rowptr[2 * tid] = excl;
    rowptr[2 * tid + 1] = excl + a;
    if (tid == 255) rowptr[512] = excl + s;
    __syncthreads();
    cnt[tid] = 0;  // reuse as fill counters
    cnt[tid + 256] = 0;
    __syncthreads();
    for (uint i = tid; i < tot; i += 256) {
        uint u = pairs[i];
        uint dl = u >> 17;
        uint pos = rowptr[dl] + atomicAdd(&cnt[dl], 1u);
        nbrG[(size_t)p * PCAP + pos] = (int)(u & 0x1FFFFu);  // L2-hot 35 KB window
    }
    #pragma unroll
    for (int t = tid; t < PART; t += 256) {
        int n = p * PART + t;
        if (n < NN) {
            uint deg = rowptr[t + 1] - rowptr[t];
            pack[n] = ((uint)(p * PCAP) + rowptr[t]) | (deg << 21);
        }
    }
}

// ---------------- casts ----------------

// x [NN][128] fp32 -> plane-sliced bf16: xb[p][n][16], p = blockIdx.y in [0,8)
__global__ __launch_bounds__(256) void k_castx(const float* __restrict__ x, ushort* __restrict__ xb) {
    int n = blockIdx.x * 256 + threadIdx.x;
    int p = blockIdx.y;
    if (n >= NN) return;
    const float4* sp = (const float4*)(x + (size_t)n * 128 + p * 16);
    uint4 o[2];
    ushort* op = (ushort*)o;
    #pragma unroll
    for (int q = 0; q < 4; ++q) {
        float4 v = sp[q];
        op[q * 4 + 0] = f2b(v.x);
        op[q * 4 + 1] = f2b(v.y);
        op[q * 4 + 2] = f2b(v.z);
        op[q * 4 + 3] = f2b(v.w);
    }
    uint4* dp = (uint4*)(xb + ((size_t)p * NN + n) * 16);
    dp[0] = o[0];
    dp[1] = o[1];
}

// Bt[n][k] (n-major, K=256 contiguous): k<128 -> Wl[k][n], else Wr[k-128][n]
__global__ __launch_bounds__(256) void k_castw(const float* __restrict__ Wl, const float* __restrict__ Wr,
                                               ushort* __restrict__ Bt) {
    int i = blockIdx.x * 256 + threadIdx.x;  // 128*256
    int n = i >> 8, k = i & 255;
    float v = (k < 128) ? Wl[k * 128 + n] : Wr[(k - 128) * 128 + n];
    Bt[i] = f2b(v);
}

// ---------------- mean aggregation: LDS-staged neighbor slab ----------------
// grid (8, NN/128); plane = blockIdx.x pins plane<->XCD via linear%8.
// 2 lanes per node (16ch plane = 2 x uint4), 128 nodes per block.
// Block's 128 consecutive nodes have a CONTIGUOUS neighbor slab in the
// partition-padded CSR -> stage it in LDS, then gathers unroll 8-deep with
// no dependence on global index loads.

__global__ __launch_bounds__(256) void k_agg(const uint4* __restrict__ feat, const int* __restrict__ nbrG,
                                             const uint* __restrict__ pack, uint4* __restrict__ outb) {
    __shared__ int sl[SLAB];
    __shared__ int sh_s0, sh_cnt;
    int plane = blockIdx.x;
    int nb = blockIdx.y * 128;  // block node range stays within one 512-partition
    int tid = threadIdx.x;
    int n = nb + (tid >> 1);
    int h = tid & 1;
    if (tid == 0) {
        uint u0 = pack[nb];
        int last = nb + 127 < NN ? nb + 127 : NN - 1;
        uint u1 = pack[last];
        int s0 = (int)(u0 & 0x1FFFFFu);
        sh_s0 = s0;
        sh_cnt = (int)(u1 & 0x1FFFFFu) + (int)(u1 >> 21) - s0;
    }
    __syncthreads();
    int s0 = sh_s0, scnt = sh_cnt;
    bool staged = scnt <= SLAB;
    if (staged) {
        for (int i = tid; i < scnt; i += 256) sl[i] = nbrG[s0 + i];
    }
    __syncthreads();
    if (n >= NN) return;
    uint u = pack[n];
    int s = (int)(u & 0x1FFFFFu);
    int d = (int)(u >> 21);
    const uint4* fp = feat + (size_t)plane * (NN * 2) + h;
    float a[8] = {};
    if (staged) {
        const int* bp = sl + (s - s0);
        int i = 0;
        for (; i + 8 <= d; i += 8) {  // 8 x 16B gathers in flight, addrs from LDS
            int c[8];
            uint4 v[8];
            #pragma unroll
            for (int j = 0; j < 8; ++j) c[j] = bp[i + j];
            #pragma unroll
            for (int j = 0; j < 8; ++j) v[j] = fp[(size_t)c[j] * 2];
            #pragma unroll
            for (int j = 0; j < 8; ++j) acc8(a, v[j]);
        }
        for (; i < d; ++i) acc8(a, fp[(size_t)bp[i] * 2]);
    } else {  // overflow fallback (P ~ 0): global index reads
        const int* bp = nbrG + s;
        int i = 0;
        for (; i + 4 <= d; i += 4) {
            int c0 = bp[i], c1 = bp[i + 1], c2 = bp[i + 2], c3 = bp[i + 3];
            uint4 v0 = fp[(size_t)c0 * 2];
            uint4 v1 = fp[(size_t)c1 * 2];
            uint4 v2 = fp[(size_t)c2 * 2];
            uint4 v3 = fp[(size_t)c3 * 2];
            acc8(a, v0);
            acc8(a, v1);
            acc8(a, v2);
            acc8(a, v3);
        }
        for (; i < d; ++i) acc8(a, fp[(size_t)bp[i] * 2]);
    }
    float id = 1.0f / fmaxf((float)d, 1.0f);
    uint4 r;
    r.x = (uint)f2b(a[0] * id) | ((uint)f2b(a[1] * id) << 16);
    r.y = (uint)f2b(a[2] * id) | ((uint)f2b(a[3] * id) << 16);
    r.z = (uint)f2b(a[4] * id) | ((uint)f2b(a[5] * id) << 16);
    r.w = (uint)f2b(a[6] * id) | ((uint)f2b(a[7] * id) << 16);
    outb[((size_t)plane * NN + n) * 2 + h] = r;
}

// ---------------- MFMA GEMM: out = relu([Am | Ax] @ Bt^T + bias) ----------------
// A operands plane-sliced [8][N][16] bf16. M x 128, K=256. BM=128/block, 32 rows/wave.

template <bool WB16>
__global__ __launch_bounds__(256) void k_gemm(const ushort* __restrict__ Am, const ushort* Ax,
                                              const ushort* __restrict__ Bt, const float* __restrict__ bias,
                                              void* outp, int M) {
    int lane = threadIdx.x & 63;
    int wave = threadIdx.x >> 6;
    int bm = blockIdx.x * 128 + wave * 32;
    int l16 = lane & 15;
    int lk8 = (lane >> 4) * 8;

    f32x4 acc[2][8] = {};
    #pragma unroll
    for (int kt = 0; kt < 8; ++kt) {
        const ushort* A = (kt < 4) ? Am : Ax;
        int kA = (kt & 3) * 32 + lk8;           // channel offset in [0,128), multiple of 8
        int p = kA >> 4, ko = kA & 15;          // plane (16ch), offset within plane row
        bf16x8 af[2];
        #pragma unroll
        for (int mt = 0; mt < 2; ++mt) {
            int row = bm + mt * 16 + l16;
            row = row < M ? row : M - 1;
            af[mt] = *(const bf16x8*)(A + ((size_t)p * NN + row) * 16 + ko);
        }
        int kB = kt * 32 + lk8;
        #pragma unroll
        for (int nt = 0; nt < 8; ++nt) {
            bf16x8 bfr = *(const bf16x8*)(Bt + (size_t)(nt * 16 + l16) * 256 + kB);
            acc[0][nt] = __builtin_amdgcn_mfma_f32_16x16x32_bf16(af[0], bfr, acc[0][nt], 0, 0, 0);
            acc[1][nt] = __builtin_amdgcn_mfma_f32_16x16x32_bf16(af[1], bfr, acc[1][nt], 0, 0, 0);
        }
    }
    // C/D layout: col = lane&15, row = (lane>>4)*4 + reg
    int mr0 = (lane >> 4) * 4;
    #pragma unroll
    for (int mt = 0; mt < 2; ++mt) {
        #pragma unroll
        for (int r = 0; r < 4; ++r) {
            int m = bm + mt * 16 + mr0 + r;
            if (m < M) {
                #pragma unroll
                for (int nt = 0; nt < 8; ++nt) {
                    float v = acc[mt][nt][r] + bias[nt * 16 + l16];
                    v = v > 0.f ? v : 0.f;
                    if (WB16) {
                        // h plane-sliced: plane = nt, ch = l16
                        ((ushort*)outp)[((size_t)nt * NN + m) * 16 + l16] = f2b(v);
                    } else {
                        ((float*)outp)[(size_t)m * 128 + nt * 16 + l16] = v;
                    }
                }
            }
        }
    }
}

// ---------------- launch ----------------

static inline size_t alignup(size_t x) { return (x + 255) & ~(size_t)255; }

extern "C" void kernel_launch(void* const* d_in, const int* in_sizes, int n_in,
                              void* d_out, int out_size, void* d_ws, size_t ws_size,
                              hipStream_t stream) {
    const float* x   = (const float*)d_in[0];
    const int* edge  = (const int*)d_in[1];
    const float* Wl1 = (const float*)d_in[2];
    const float* Wr1 = (const float*)d_in[3];
    const float* b1  = (const float*)d_in[4];
    const float* Wl2 = (const float*)d_in[5];
    const float* Wr2 = (const float*)d_in[6];
    const float* b2  = (const float*)d_in[7];
    float* out = (float*)d_out;

    const int* srcp = edge;
    const int* dstp = edge + NE;

    // pairbuf + partition-padded CSR live in d_out (13.6 MB of 51.2 MB);
    // both dead before gemm2 writes the real output.
    uint* pairbuf = (uint*)d_out;                       // NP*PCAP uints = 6.8 MB
    int* nbrG = (int*)d_out + (size_t)NP * PCAP;        // NP*PCAP ints  = 6.8 MB

    char* w = (char*)d_ws;
    uint* pcnt = (uint*)w;    w += alignup((size_t)NP * 4);
    uint* pack = (uint*)w;    w += alignup((size_t)NN * 4);
    ushort* xb = (ushort*)w;  w += alignup((size_t)NN * CH * 2);  // plane-sliced; reused as h
    ushort* mb = (ushort*)w;  w += alignup((size_t)NN * CH * 2);  // plane-sliced mean
    ushort* Bt1 = (ushort*)w; w += alignup((size_t)128 * 256 * 2);
    ushort* Bt2 = (ushort*)w; w += alignup((size_t)128 * 256 * 2);

    hipMemsetAsync(pcnt, 0, (size_t)NP * 4, stream);

    k_bin<<<NB, 1024, 0, stream>>>(srcp, dstp, pcnt, pairbuf);
    k_csr<<<NP, 256, 0, stream>>>(pcnt, pairbuf, nbrG, pack);

    k_castx<<<dim3((NN + 255) / 256, 8), 256, 0, stream>>>(x, xb);
    k_castw<<<128, 256, 0, stream>>>(Wl1, Wr1, Bt1);
    k_castw<<<128, 256, 0, stream>>>(Wl2, Wr2, Bt2);

    int gg = (NN + 127) / 128;
    dim3 ag(8, (NN + 127) / 128);
    // layer 1: agg(xb) -> mb; h = relu([mb|xb]@B1) bf16 plane-sliced, in place over xb
    k_agg<<<ag, 256, 0, stream>>>((const uint4*)xb, nbrG, pack, (uint4*)mb);
    k_gemm<true><<<gg, 256, 0, stream>>>(mb, xb, Bt1, b1, (void*)xb, NN);
    // layer 2: agg(h) -> mb; out = relu([mb|h]@B2) fp32 row-major (overwrites pairbuf/nbrG)
    k_agg<<<ag, 256, 0, stream>>>((const uint4*)xb, nbrG, pack, (uint4*)mb);
    k_gemm<false><<<gg, 256, 0, stream>>>(mb, xb, Bt2, b2, (void*)out, NN);
}

// Round 8
// 357.360 us; speedup vs baseline: 1.3844x; 1.0740x over previous
//
#include <hip/hip_runtime.h>

#define NN 100000
#define NE 1600000
#define CH 128

#define PART 512               // nodes per partition
#define NP 196                 // ceil(NN/PART)
#define PCAP 8704              // pair capacity per partition (lambda~8163, +6 sd)
#define EPB 4096               // edges per bin block
#define NB 391                 // ceil(NE/EPB)
#define SCAP 64                // LDS slot cap per (block, partition); lambda~21
#define SLAB 3072              // agg: LDS slab cap (128 nodes, lambda~2048, +22 sd)

typedef __attribute__((ext_vector_type(8))) short bf16x8;
typedef __attribute__((ext_vector_type(4))) float f32x4;
typedef unsigned int uint;
typedef unsigned short ushort;

__device__ __forceinline__ ushort f2b(float f) {
    uint u = __builtin_bit_cast(uint, f);
    uint r = (u + 0x7fff + ((u >> 16) & 1)) >> 16;
    return (ushort)r;
}
__device__ __forceinline__ float blo(uint v) { return __builtin_bit_cast(float, v << 16); }
__device__ __forceinline__ float bhi(uint v) { return __builtin_bit_cast(float, v & 0xffff0000u); }

__device__ __forceinline__ void acc8(float* a, uint4 v) {
    a[0] += blo(v.x); a[1] += bhi(v.x);
    a[2] += blo(v.y); a[3] += bhi(v.y);
    a[4] += blo(v.z); a[5] += bhi(v.z);
    a[6] += blo(v.w); a[7] += bhi(v.w);
}

// ---------------- pass 1: LDS-binned edge partitioning ----------------
// pair = (dst_local << 17) | src ; partition p = dst >> 9. int4 edge reads.

__global__ __launch_bounds__(1024) void k_bin(const int4* __restrict__ src4, const int4* __restrict__ dst4,
                                              uint* __restrict__ pcnt, uint* __restrict__ pairbuf) {
    __shared__ uint slots[NP * SCAP];  // 50.2 KB
    __shared__ uint lcnt[NP];
    __shared__ uint lbase[NP];
    int tid = threadIdx.x;
    if (tid < NP) lcnt[tid] = 0;
    __syncthreads();
    int e4 = blockIdx.x * 1024 + tid;
    if (e4 < NE / 4) {
        int4 d4 = dst4[e4];
        int4 s4 = src4[e4];
        int dd[4] = {d4.x, d4.y, d4.z, d4.w};
        int ss[4] = {s4.x, s4.y, s4.z, s4.w};
        #pragma unroll
        for (int j = 0; j < 4; ++j) {
            int p = dd[j] >> 9;
            uint pair = ((uint)(dd[j] & 511) << 17) | (uint)ss[j];
            uint pos = atomicAdd(&lcnt[p], 1u);
            if (pos < SCAP) slots[p * SCAP + pos] = pair;
        }
    }
    __syncthreads();
    if (tid < NP) {
        uint c = lcnt[tid];
        c = c < SCAP ? c : SCAP;
        lcnt[tid] = c;
        lbase[tid] = atomicAdd(&pcnt[tid], c);
    }
    __syncthreads();
    for (int t = tid; t < NP * SCAP; t += 1024) {
        int p = t >> 6;
        uint s = (uint)(t & (SCAP - 1));
        if (s < lcnt[p]) {
            uint idx = lbase[p] + s;
            if (idx < PCAP) pairbuf[(size_t)p * PCAP + idx] = slots[t];
        }
    }
}

// ---------------- pass 2: per-partition LDS CSR build (512 thr) ----------------
// Emits nbrG (partition-padded CSR, coalesced) + pack[n] = start | (deg<<21).

__global__ __launch_bounds__(512) void k_csr(const uint* __restrict__ pcnt, const uint* __restrict__ pairbuf,
                                             int* __restrict__ nbrG, uint* __restrict__ pack) {
    __shared__ uint pairs[PCAP];   // 34.8 KB
    __shared__ uint cnt[PART];
    __shared__ uint rowptr[PART + 1];
    __shared__ uint tsum[PART];
    int tid = threadIdx.x;
    int p = blockIdx.x;
    uint tot = pcnt[p];
    tot = tot < PCAP ? tot : PCAP;
    for (uint i = tid; i < tot; i += 512) pairs[i] = pairbuf[(size_t)p * PCAP + i];
    cnt[tid] = 0;
    __syncthreads();
    for (uint i = tid; i < tot; i += 512) atomicAdd(&cnt[pairs[i] >> 17], 1u);
    __syncthreads();
    // exclusive scan over 512 counters, one per thread
    uint s = cnt[tid];
    tsum[tid] = s;
    __syncthreads();
    for (int off = 1; off < 512; off <<= 1) {
        uint t = (tid >= off) ? tsum[tid - off] : 0;
        __syncthreads();
        tsum[tid] += t;
        __syncthreads();
    }
    rowptr[tid] = tsum[tid] - s;
    if (tid == 511) rowptr[512] = tsum[511];
    __syncthreads();
    cnt[tid] = 0;  // reuse as fill counters
    __syncthreads();
    for (uint i = tid; i < tot; i += 512) {
        uint u = pairs[i];
        uint dl = u >> 17;
        uint pos = rowptr[dl] + atomicAdd(&cnt[dl], 1u);
        nbrG[(size_t)p * PCAP + pos] = (int)(u & 0x1FFFFu);  // L2-hot 35 KB window
    }
    {
        int n = p * PART + tid;
        if (n < NN) {
            uint deg = rowptr[tid + 1] - rowptr[tid];
            pack[n] = ((uint)(p * PCAP) + rowptr[tid]) | (deg << 21);
        }
    }
}

// ---------------- casts ----------------

// x [NN][128] fp32 -> plane-sliced bf16: xb[p][n][16], p = blockIdx.y in [0,8)
__global__ __launch_bounds__(256) void k_castx(const float* __restrict__ x, ushort* __restrict__ xb) {
    int n = blockIdx.x * 256 + threadIdx.x;
    int p = blockIdx.y;
    if (n >= NN) return;
    const float4* sp = (const float4*)(x + (size_t)n * 128 + p * 16);
    uint4 o[2];
    ushort* op = (ushort*)o;
    #pragma unroll
    for (int q = 0; q < 4; ++q) {
        float4 v = sp[q];
        op[q * 4 + 0] = f2b(v.x);
        op[q * 4 + 1] = f2b(v.y);
        op[q * 4 + 2] = f2b(v.z);
        op[q * 4 + 3] = f2b(v.w);
    }
    uint4* dp = (uint4*)(xb + ((size_t)p * NN + n) * 16);
    dp[0] = o[0];
    dp[1] = o[1];
}

// k-major B: BtK[kt][n][c] = (k<128 ? Wl[k][n] : Wr[k-128][n]), k = kt*32+c.
// Each 8 KB kt-slice is contiguous -> L1-resident during the gemm kt-iteration.
// blockIdx.y selects layer (Wl1/Wr1->BtK1 vs Wl2/Wr2->BtK2).
__global__ __launch_bounds__(256) void k_castw(const float* __restrict__ Wl1, const float* __restrict__ Wr1,
                                               const float* __restrict__ Wl2, const float* __restrict__ Wr2,
                                               ushort* __restrict__ BtK1, ushort* __restrict__ BtK2) {
    int i = blockIdx.x * 256 + threadIdx.x;  // over 8*128*32 = 32768
    const float* Wl = blockIdx.y ? Wl2 : Wl1;
    const float* Wr = blockIdx.y ? Wr2 : Wr1;
    ushort* BtK = blockIdx.y ? BtK2 : BtK1;
    int c = i & 31;
    int n = (i >> 5) & 127;
    int kt = i >> 12;
    int k = kt * 32 + c;
    float v = (k < 128) ? Wl[k * 128 + n] : Wr[(k - 128) * 128 + n];
    BtK[i] = f2b(v);
}

// ---------------- mean aggregation: LDS-staged neighbor slab ----------------
// grid (8, NN/128); plane = blockIdx.x pins plane<->XCD via linear%8.
// 2 lanes per node (16ch plane = 2 x uint4), 128 nodes per block.

__global__ __launch_bounds__(256) void k_agg(const uint4* __restrict__ feat, const int* __restrict__ nbrG,
                                             const uint* __restrict__ pack, uint4* __restrict__ outb) {
    __shared__ int sl[SLAB];
    __shared__ int sh_s0, sh_cnt;
    int plane = blockIdx.x;
    int nb = blockIdx.y * 128;  // block node range stays within one 512-partition
    int tid = threadIdx.x;
    int n = nb + (tid >> 1);
    int h = tid & 1;
    if (tid == 0) {
        uint u0 = pack[nb];
        int last = nb + 127 < NN ? nb + 127 : NN - 1;
        uint u1 = pack[last];
        int s0 = (int)(u0 & 0x1FFFFFu);
        sh_s0 = s0;
        sh_cnt = (int)(u1 & 0x1FFFFFu) + (int)(u1 >> 21) - s0;
    }
    __syncthreads();
    int s0 = sh_s0, scnt = sh_cnt;
    bool staged = scnt <= SLAB;
    if (staged) {
        for (int i = tid; i < scnt; i += 256) sl[i] = nbrG[s0 + i];
    }
    __syncthreads();
    if (n >= NN) return;
    uint u = pack[n];
    int s = (int)(u & 0x1FFFFFu);
    int d = (int)(u >> 21);
    const uint4* fp = feat + (size_t)plane * (NN * 2) + h;
    float a[8] = {};
    if (staged) {
        const int* bp = sl + (s - s0);
        int i = 0;
        for (; i + 8 <= d; i += 8) {  // 8 x 16B gathers in flight, addrs from LDS
            int c[8];
            uint4 v[8];
            #pragma unroll
            for (int j = 0; j < 8; ++j) c[j] = bp[i + j];
            #pragma unroll
            for (int j = 0; j < 8; ++j) v[j] = fp[(size_t)c[j] * 2];
            #pragma unroll
            for (int j = 0; j < 8; ++j) acc8(a, v[j]);
        }
        for (; i < d; ++i) acc8(a, fp[(size_t)bp[i] * 2]);
    } else {  // overflow fallback (P ~ 0): global index reads
        const int* bp = nbrG + s;
        int i = 0;
        for (; i + 4 <= d; i += 4) {
            int c0 = bp[i], c1 = bp[i + 1], c2 = bp[i + 2], c3 = bp[i + 3];
            uint4 v0 = fp[(size_t)c0 * 2];
            uint4 v1 = fp[(size_t)c1 * 2];
            uint4 v2 = fp[(size_t)c2 * 2];
            uint4 v3 = fp[(size_t)c3 * 2];
            acc8(a, v0);
            acc8(a, v1);
            acc8(a, v2);
            acc8(a, v3);
        }
        for (; i < d; ++i) acc8(a, fp[(size_t)bp[i] * 2]);
    }
    float id = 1.0f / fmaxf((float)d, 1.0f);
    uint4 r;
    r.x = (uint)f2b(a[0] * id) | ((uint)f2b(a[1] * id) << 16);
    r.y = (uint)f2b(a[2] * id) | ((uint)f2b(a[3] * id) << 16);
    r.z = (uint)f2b(a[4] * id) | ((uint)f2b(a[5] * id) << 16);
    r.w = (uint)f2b(a[6] * id) | ((uint)f2b(a[7] * id) << 16);
    outb[((size_t)plane * NN + n) * 2 + h] = r;
}

// ---------------- MFMA GEMM: out = relu([Am | Ax] @ B + bias) ----------------
// A plane-sliced [8][N][16] bf16; B k-major [8][128][32]. BM=128/block, 32 rows/wave.

template <bool WB16>
__global__ __launch_bounds__(256) void k_gemm(const ushort* __restrict__ Am, const ushort* Ax,
                                              const ushort* __restrict__ BtK, const float* __restrict__ bias,
                                              void* outp, int M) {
    int lane = threadIdx.x & 63;
    int wave = threadIdx.x >> 6;
    int bm = blockIdx.x * 128 + wave * 32;
    int l16 = lane & 15;
    int lk8 = (lane >> 4) * 8;

    f32x4 acc[2][8] = {};
    #pragma unroll
    for (int kt = 0; kt < 8; ++kt) {
        const ushort* A = (kt < 4) ? Am : Ax;
        int kA = (kt & 3) * 32 + lk8;           // channel offset in [0,128), multiple of 8
        int p = kA >> 4, ko = kA & 15;          // plane (16ch), offset within plane row
        bf16x8 af[2];
        #pragma unroll
        for (int mt = 0; mt < 2; ++mt) {
            int row = bm + mt * 16 + l16;
            row = row < M ? row : M - 1;
            af[mt] = *(const bf16x8*)(A + ((size_t)p * NN + row) * 16 + ko);
        }
        const ushort* Bk = BtK + (size_t)kt * 128 * 32;  // contiguous 8 KB slice, L1-hot
        #pragma unroll
        for (int nt = 0; nt < 8; ++nt) {
            bf16x8 bfr = *(const bf16x8*)(Bk + (size_t)(nt * 16 + l16) * 32 + lk8);
            acc[0][nt] = __builtin_amdgcn_mfma_f32_16x16x32_bf16(af[0], bfr, acc[0][nt], 0, 0, 0);
            acc[1][nt] = __builtin_amdgcn_mfma_f32_16x16x32_bf16(af[1], bfr, acc[1][nt], 0, 0, 0);
        }
    }
    // C/D layout: col = lane&15, row = (lane>>4)*4 + reg
    int mr0 = (lane >> 4) * 4;
    #pragma unroll
    for (int mt = 0; mt < 2; ++mt) {
        #pragma unroll
        for (int r = 0; r < 4; ++r) {
            int m = bm + mt * 16 + mr0 + r;
            if (m < M) {
                #pragma unroll
                for (int nt = 0; nt < 8; ++nt) {
                    float v = acc[mt][nt][r] + bias[nt * 16 + l16];
                    v = v > 0.f ? v : 0.f;
                    if (WB16) {
                        // h plane-sliced: plane = nt, ch = l16
                        ((ushort*)outp)[((size_t)nt * NN + m) * 16 + l16] = f2b(v);
                    } else {
                        ((float*)outp)[(size_t)m * 128 + nt * 16 + l16] = v;
                    }
                }
            }
        }
    }
}

// ---------------- launch ----------------

static inline size_t alignup(size_t x) { return (x + 255) & ~(size_t)255; }

extern "C" void kernel_launch(void* const* d_in, const int* in_sizes, int n_in,
                              void* d_out, int out_size, void* d_ws, size_t ws_size,
                              hipStream_t stream) {
    const float* x   = (const float*)d_in[0];
    const int* edge  = (const int*)d_in[1];
    const float* Wl1 = (const float*)d_in[2];
    const float* Wr1 = (const float*)d_in[3];
    const float* b1  = (const float*)d_in[4];
    const float* Wl2 = (const float*)d_in[5];
    const float* Wr2 = (const float*)d_in[6];
    const float* b2  = (const float*)d_in[7];
    float* out = (float*)d_out;

    const int* srcp = edge;
    const int* dstp = edge + NE;

    // pairbuf + partition-padded CSR live in d_out (13.6 MB of 51.2 MB);
    // both dead before gemm2 writes the real output.
    uint* pairbuf = (uint*)d_out;                       // NP*PCAP uints = 6.8 MB
    int* nbrG = (int*)d_out + (size_t)NP * PCAP;        // NP*PCAP ints  = 6.8 MB

    char* w = (char*)d_ws;
    uint* pcnt = (uint*)w;     w += alignup((size_t)NP * 4);
    uint* pack = (uint*)w;     w += alignup((size_t)NN * 4);
    ushort* xb = (ushort*)w;   w += alignup((size_t)NN * CH * 2);  // plane-sliced; reused as h
    ushort* mb = (ushort*)w;   w += alignup((size_t)NN * CH * 2);  // plane-sliced mean
    ushort* BtK1 = (ushort*)w; w += alignup((size_t)128 * 256 * 2);
    ushort* BtK2 = (ushort*)w; w += alignup((size_t)128 * 256 * 2);

    hipMemsetAsync(pcnt, 0, (size_t)NP * 4, stream);

    k_bin<<<NB, 1024, 0, stream>>>((const int4*)srcp, (const int4*)dstp, pcnt, pairbuf);
    k_csr<<<NP, 512, 0, stream>>>(pcnt, pairbuf, nbrG, pack);

    k_castx<<<dim3((NN + 255) / 256, 8), 256, 0, stream>>>(x, xb);
    k_castw<<<dim3(128, 2), 256, 0, stream>>>(Wl1, Wr1, Wl2, Wr2, BtK1, BtK2);

    int gg = (NN + 127) / 128;
    dim3 ag(8, (NN + 127) / 128);
    // layer 1: agg(xb) -> mb; h = relu([mb|xb]@B1) bf16 plane-sliced, in place over xb
    k_agg<<<ag, 256, 0, stream>>>((const uint4*)xb, nbrG, pack, (uint4*)mb);
    k_gemm<true><<<gg, 256, 0, stream>>>(mb, xb, BtK1, b1, (void*)xb, NN);
    // layer 2: agg(h) -> mb; out = relu([mb|h]@B2) fp32 row-major (overwrites pairbuf/nbrG)
    k_agg<<<ag, 256, 0, stream>>>((const uint4*)xb, nbrG, pack, (uint4*)mb);
    k_gemm<false><<<gg, 256, 0, stream>>>(mb, xb, BtK2, b2, (void*)out, NN);
}